// Round 1
// baseline (5880.215 us; speedup 1.0000x reference)
//
#include <hip/hip_runtime.h>
#include <hip/hip_bf16.h>

// GAT round 0: correct fp32 baseline.
// Structure: pack mask bits -> gemm (A@feats) -> gemm (xW1^T+b) -> src/dst ->
// fused 2-pass attention (flash-style, no NxN materialization) -> gemm (xW2^T+b)
// -> src/dst -> attention (per-head planes) -> elu+colmean -> final dot.
// All fp32 VALU; MFMA conversion planned for later rounds.

#define NN 4096
#define FF 512
#define HH 256
#define KK 8
#define KH 2048  // KK*HH

// ---------------- mask pack: adjacency fp32 -> bitmask (2 MB) ----------------
__global__ void pack_mask_kernel(const float* __restrict__ adj,
                                 unsigned int* __restrict__ mbits) {
    int i = blockIdx.x;
    int lane = threadIdx.x & 63;
    int wv = threadIdx.x >> 6;  // 0..3
    for (int j0 = wv * 64; j0 < NN; j0 += 256) {
        float v = adj[(size_t)i * NN + j0 + lane];
        unsigned long long b = __ballot(v == 1.0f);
        if (lane == 0) {
            mbits[i * 128 + (j0 >> 5)]     = (unsigned int)(b & 0xffffffffull);
            mbits[i * 128 + (j0 >> 5) + 1] = (unsigned int)(b >> 32);
        }
    }
}

// ---------------- fp32 tiled GEMM: C = A@B (+bias), optional B^T ----------------
// 64x64 tile, BK=16, 256 threads, 4x4 per thread. All dims multiples of 64/16.
template <int TRANSB>
__global__ __launch_bounds__(256) void gemm64_kernel(
    const float* __restrict__ A, const float* __restrict__ B,
    const float* __restrict__ bias, float* __restrict__ C,
    int M, int Nn, int Ksz) {
    __shared__ __align__(16) float As[16][68];
    __shared__ __align__(16) float Bs[16][68];
    int t = threadIdx.x;
    int tx = t & 15, ty = t >> 4;
    int n0 = blockIdx.x * 64, m0 = blockIdx.y * 64;
    float acc[4][4] = {};
    for (int k0 = 0; k0 < Ksz; k0 += 16) {
        {   // A tile (transposed store into As[k][m])
            int row = t >> 2, kq = (t & 3) * 4;
            float4 a4 = *(const float4*)&A[(size_t)(m0 + row) * Ksz + k0 + kq];
            As[kq + 0][row] = a4.x; As[kq + 1][row] = a4.y;
            As[kq + 2][row] = a4.z; As[kq + 3][row] = a4.w;
        }
        if (TRANSB) {  // B is [Nn, Ksz] row-major; Bs[k][n] = B[n][k]
            int nrow = t >> 2, kq = (t & 3) * 4;
            float4 b4 = *(const float4*)&B[(size_t)(n0 + nrow) * Ksz + k0 + kq];
            Bs[kq + 0][nrow] = b4.x; Bs[kq + 1][nrow] = b4.y;
            Bs[kq + 2][nrow] = b4.z; Bs[kq + 3][nrow] = b4.w;
        } else {       // B is [Ksz, Nn] row-major
            int krow = t >> 4, cq = (t & 15) * 4;
            float4 b4 = *(const float4*)&B[(size_t)(k0 + krow) * Nn + n0 + cq];
            *(float4*)&Bs[krow][cq] = b4;
        }
        __syncthreads();
#pragma unroll
        for (int kk = 0; kk < 16; kk++) {
            float4 av = *(float4*)&As[kk][ty * 4];
            float4 bv = *(float4*)&Bs[kk][tx * 4];
            float a[4] = {av.x, av.y, av.z, av.w};
            float b[4] = {bv.x, bv.y, bv.z, bv.w};
#pragma unroll
            for (int i = 0; i < 4; i++)
#pragma unroll
                for (int j = 0; j < 4; j++) acc[i][j] += a[i] * b[j];
        }
        __syncthreads();
    }
#pragma unroll
    for (int i = 0; i < 4; i++) {
        int m = m0 + ty * 4 + i;
        int n = n0 + tx * 4;
        float4 o;
        o.x = acc[i][0]; o.y = acc[i][1]; o.z = acc[i][2]; o.w = acc[i][3];
        if (bias) {
            o.x += bias[n + 0]; o.y += bias[n + 1];
            o.z += bias[n + 2]; o.w += bias[n + 3];
        }
        *(float4*)&C[(size_t)m * Nn + n] = o;
    }
}

// ---------------- src/dst projections: srcT[k][n], dstT[k][n] ----------------
__global__ void src_dst_kernel(const float* __restrict__ h,
                               const float* __restrict__ aw,
                               const float* __restrict__ ab,
                               float* __restrict__ srcT, float* __restrict__ dstT) {
    __shared__ __align__(16) float awl[KK * 2 * HH];  // 4096 floats = 16 KB
    int t = threadIdx.x;
    for (int q = 0; q < 4; q++) {
        int i4 = t + q * 256;
        *(float4*)&awl[i4 * 4] = *(const float4*)&aw[i4 * 4];
    }
    __syncthreads();
    int k = t & 7, nl = t >> 3;
    int n = blockIdx.x * 32 + nl;
    float s = ab[k], d = 0.f;
    const float* hp = &h[(size_t)n * HH];
    const float* ws = &awl[k * 512];
    const float* wd = ws + 256;
    for (int c = 0; c < 256; c++) {
        float hv = hp[c];
        s += hv * ws[c];
        d += hv * wd[c];
    }
    srcT[k * NN + n] = s;
    dstT[k * NN + n] = d;
}

// ---------------- fused attention (one head per blockIdx.y, 32 rows/block) ----
// MODE 1: out[i][k*HH+c] = elu(h[i][c] + sum_j alpha_ij h[j][c])   (layer 1)
// MODE 2: out[k][i][c]   = sum_j alpha_ij h[j][c]                  (layer 2 planes)
template <int MODE>
__global__ __launch_bounds__(256) void attn_kernel(
    const float* __restrict__ h, const float* __restrict__ srcT,
    const float* __restrict__ dstT, const unsigned int* __restrict__ mbits,
    float* __restrict__ out) {
    __shared__ __align__(16) float dst_l[NN];            // 16 KB
    __shared__ unsigned int mrow[32][128];               // 16 KB
    __shared__ float src_l[32];
    __shared__ float m_l[32];
    __shared__ float linv_l[32];
    __shared__ __align__(16) float htile[32][256];       // 32 KB
    __shared__ float p_l[32][33];                        // padded: avoid 16-way conflicts

    int t = threadIdx.x;
    int i0 = blockIdx.x * 32;
    int k = blockIdx.y;

    for (int q = 0; q < 4; q++) {
        int i4 = t + q * 256;
        *(float4*)&dst_l[i4 * 4] = *(const float4*)&dstT[(size_t)k * NN + i4 * 4];
    }
    if (t < 32) src_l[t] = srcT[(size_t)k * NN + i0 + t];
    for (int q = 0; q < 16; q++) {
        int idx = t + q * 256;  // 0..4095
        int r = idx >> 7, w = idx & 127;
        mrow[r][w] = mbits[(size_t)(i0 + r) * 128 + w];
    }
    __syncthreads();

    // ---- pass 1: per-row online (m, l) over all neighbors ----
    int lane = t & 63, wv = t >> 6;
    for (int rr = 0; rr < 8; rr++) {
        int r = wv * 8 + rr;
        float sv = src_l[r];
        float m = -1e30f, l = 0.f;
        for (int it = 0; it < 64; it++) {
            int j = it * 64 + lane;
            unsigned int word = mrow[r][j >> 5];
            if ((word >> (j & 31)) & 1u) {
                float x = sv + dst_l[j];
                float lg = (x >= 0.f) ? x : 0.01f * x;
                float nm = fmaxf(m, lg);
                l = l * __expf(m - nm) + __expf(lg - nm);
                m = nm;
            }
        }
        for (int off = 32; off > 0; off >>= 1) {
            float om = __shfl_down(m, off);
            float ol = __shfl_down(l, off);
            float nm = fmaxf(m, om);
            l = l * __expf(m - nm) + ol * __expf(om - nm);
            m = nm;
        }
        if (lane == 0) {
            m_l[r] = m;
            linv_l[r] = (l > 0.f) ? 1.f / l : 0.f;  // l==0: isolated row -> alpha=0
        }
    }

    // ---- pass 2: acc[i][c] = sum_j p_ij * h[j][c], 2 rows x 16 cols / thread ----
    float acc[2][16];
#pragma unroll
    for (int q = 0; q < 16; q++) { acc[0][q] = 0.f; acc[1][q] = 0.f; }
    int r2 = t >> 4;            // 0..15 -> rows r2 and r2+16
    int c0 = (t & 15) * 16;
    int jl_s = t >> 3;          // staging: row 0..31
    int seg = (t & 7) * 32;     // staging: 32-float segment

    for (int jt = 0; jt < 128; jt++) {
        int j0 = jt * 32;
        __syncthreads();
        {   // stage h[j0..j0+31][0..255] into LDS
            const float* hp = &h[(size_t)(j0 + jl_s) * HH + seg];
            float* dp = &htile[jl_s][seg];
#pragma unroll
            for (int q = 0; q < 8; q++) *(float4*)&dp[q * 4] = *(const float4*)&hp[q * 4];
        }
#pragma unroll
        for (int q = 0; q < 4; q++) {  // 32x32 p entries, 4 per thread
            int e = t + q * 256;
            int r = e >> 5, jl = e & 31;
            int j = j0 + jl;
            unsigned int word = mrow[r][j >> 5];
            float p = 0.f;
            if ((word >> (j & 31)) & 1u) {
                float x = src_l[r] + dst_l[j];
                float lg = (x >= 0.f) ? x : 0.01f * x;
                p = __expf(lg - m_l[r]) * linv_l[r];
            }
            p_l[r][jl] = p;
        }
        __syncthreads();
#pragma unroll 4
        for (int jl = 0; jl < 32; jl++) {
            float pA = p_l[r2][jl];
            float pB = p_l[r2 + 16][jl];
            const float* hr = &htile[jl][c0];
#pragma unroll
            for (int q = 0; q < 4; q++) {
                float4 hv = *(const float4*)&hr[q * 4];
                acc[0][q * 4 + 0] += pA * hv.x; acc[0][q * 4 + 1] += pA * hv.y;
                acc[0][q * 4 + 2] += pA * hv.z; acc[0][q * 4 + 3] += pA * hv.w;
                acc[1][q * 4 + 0] += pB * hv.x; acc[1][q * 4 + 1] += pB * hv.y;
                acc[1][q * 4 + 2] += pB * hv.z; acc[1][q * 4 + 3] += pB * hv.w;
            }
        }
    }

    // ---- epilogue ----
#pragma unroll
    for (int rr = 0; rr < 2; rr++) {
        int i = i0 + r2 + rr * 16;
        if (MODE == 1) {
            float4 o[4];
#pragma unroll
            for (int q = 0; q < 16; q++) {
                float v = h[(size_t)i * HH + c0 + q] + acc[rr][q];
                v = (v > 0.f) ? v : (__expf(v) - 1.f);  // elu
                ((float*)o)[q] = v;
            }
#pragma unroll
            for (int q = 0; q < 4; q++)
                *(float4*)&out[(size_t)i * KH + (size_t)k * HH + c0 + q * 4] = o[q];
        } else {
#pragma unroll
            for (int q = 0; q < 4; q++) {
                float4 o;
                o.x = acc[rr][q * 4 + 0]; o.y = acc[rr][q * 4 + 1];
                o.z = acc[rr][q * 4 + 2]; o.w = acc[rr][q * 4 + 3];
                *(float4*)&out[(size_t)k * NN * HH + (size_t)i * HH + c0 + q * 4] = o;
            }
        }
    }
}

// ---------------- elu(avg of heads) column partial sums ----------------
__global__ void colsum_kernel(const float* __restrict__ h2,
                              const float* __restrict__ heads,
                              float* __restrict__ partial) {
    int c = threadIdx.x;
    int b = blockIdx.x;
    float s = 0.f;
    for (int il = 0; il < 64; il++) {
        int i = b * 64 + il;
        float v = h2[(size_t)i * HH + c];
#pragma unroll
        for (int k = 0; k < KK; k++)
            v += 0.125f * heads[(size_t)k * NN * HH + (size_t)i * HH + c];
        s += (v > 0.f) ? v : (__expf(v) - 1.f);  // elu before the row-mean
    }
    partial[b * HH + c] = s;
}

__global__ void final_kernel(const float* __restrict__ partial,
                             const float* __restrict__ out_w,
                             const float* __restrict__ out_b,
                             float* __restrict__ dout) {
    __shared__ float red[256];
    int c = threadIdx.x;
    float s = 0.f;
    for (int b = 0; b < 64; b++) s += partial[b * HH + c];
    red[c] = (s / 4096.f) * out_w[c];
    __syncthreads();
    for (int off = 128; off > 0; off >>= 1) {
        if (c < off) red[c] += red[c + off];
        __syncthreads();
    }
    if (c == 0) dout[0] = red[0] + out_b[0];
}

extern "C" void kernel_launch(void* const* d_in, const int* in_sizes, int n_in,
                              void* d_out, int out_size, void* d_ws, size_t ws_size,
                              hipStream_t stream) {
    (void)in_sizes; (void)n_in; (void)out_size; (void)ws_size;
    const float* adj   = (const float*)d_in[0];
    const float* feats = (const float*)d_in[1];
    const float* W1_w  = (const float*)d_in[2];
    const float* W1_b  = (const float*)d_in[3];
    const float* a1_w  = (const float*)d_in[4];
    const float* a1_b  = (const float*)d_in[5];
    const float* W2_w  = (const float*)d_in[6];
    const float* W2_b  = (const float*)d_in[7];
    const float* a2_w  = (const float*)d_in[8];
    const float* a2_b  = (const float*)d_in[9];
    const float* out_w = (const float*)d_in[10];
    const float* out_b = (const float*)d_in[11];

    char* w = (char*)d_ws;
    unsigned int* mbits = (unsigned int*)w;                         // 2 MB
    float* tmp1    = (float*)(w + (2ull  << 20));                   // 8 MB  [N,F]
    float* h1      = (float*)(w + (10ull << 20));                   // 4 MB  [N,H]
    float* srcT    = (float*)(w + (14ull << 20));                   // 128 KB [K,N]
    float* dstT    = (float*)(w + (14ull << 20) + (128ull << 10));  // 128 KB
    float* h1n     = (float*)(w + (15ull << 20));                   // 32 MB [N,K*H] (reused as head planes)
    float* h2      = (float*)(w + (47ull << 20));                   // 4 MB  [N,H]
    float* partial = (float*)(w + (51ull << 20));                   // 64 KB

    pack_mask_kernel<<<NN, 256, 0, stream>>>(adj, mbits);
    // tmp1 = A @ feats
    gemm64_kernel<0><<<dim3(FF / 64, NN / 64), 256, 0, stream>>>(
        adj, feats, nullptr, tmp1, NN, FF, NN);
    // h1 = tmp1 @ W1^T + b1
    gemm64_kernel<1><<<dim3(HH / 64, NN / 64), 256, 0, stream>>>(
        tmp1, W1_w, W1_b, h1, NN, HH, FF);
    src_dst_kernel<<<NN / 32, 256, 0, stream>>>(h1, a1_w, a1_b, srcT, dstT);
    // layer-1 attention -> h1n = elu(concat heads)
    attn_kernel<1><<<dim3(NN / 32, KK), 256, 0, stream>>>(h1, srcT, dstT, mbits, h1n);
    // h2 = h1n @ W2^T + b2
    gemm64_kernel<1><<<dim3(HH / 64, NN / 64), 256, 0, stream>>>(
        h1n, W2_w, W2_b, h2, NN, HH, KH);
    src_dst_kernel<<<NN / 32, 256, 0, stream>>>(h2, a2_w, a2_b, srcT, dstT);
    // layer-2 attention -> per-head planes (reuse h1n scratch; h1n already consumed)
    attn_kernel<2><<<dim3(NN / 32, KK), 256, 0, stream>>>(h2, srcT, dstT, mbits, h1n);
    colsum_kernel<<<64, 256, 0, stream>>>(h2, h1n, partial);
    final_kernel<<<1, 256, 0, stream>>>(partial, out_w, out_b, (float*)d_out);
}

// Round 2
// 849.279 us; speedup vs baseline: 6.9238x; 6.9238x over previous
//
#include <hip/hip_runtime.h>
#include <hip/hip_bf16.h>

// GAT round 1: bf16-MFMA attention (register P-fragments, pre-swizzled B), rest unchanged.

#define NN 4096
#define FF 512
#define HH 256
#define KK 8
#define KH 2048  // KK*HH

typedef __attribute__((ext_vector_type(8))) short bf16x8;
typedef __attribute__((ext_vector_type(4))) float f32x4;

__device__ inline short f2bf(float x) {
    __hip_bfloat16 b = __float2bfloat16(x);
    return *reinterpret_cast<short*>(&b);
}

// ---------------- mask pack: adjacency fp32 -> bitmask (2 MB) ----------------
__global__ void pack_mask_kernel(const float* __restrict__ adj,
                                 unsigned int* __restrict__ mbits) {
    int i = blockIdx.x;
    int lane = threadIdx.x & 63;
    int wv = threadIdx.x >> 6;  // 0..3
    for (int j0 = wv * 64; j0 < NN; j0 += 256) {
        float v = adj[(size_t)i * NN + j0 + lane];
        unsigned long long b = __ballot(v == 1.0f);
        if (lane == 0) {
            mbits[i * 128 + (j0 >> 5)]     = (unsigned int)(b & 0xffffffffull);
            mbits[i * 128 + (j0 >> 5) + 1] = (unsigned int)(b >> 32);
        }
    }
}

// ---------------- fp32 tiled GEMM: C = A@B (+bias), optional B^T ----------------
template <int TRANSB>
__global__ __launch_bounds__(256) void gemm64_kernel(
    const float* __restrict__ A, const float* __restrict__ B,
    const float* __restrict__ bias, float* __restrict__ C,
    int M, int Nn, int Ksz) {
    __shared__ __align__(16) float As[16][68];
    __shared__ __align__(16) float Bs[16][68];
    int t = threadIdx.x;
    int tx = t & 15, ty = t >> 4;
    int n0 = blockIdx.x * 64, m0 = blockIdx.y * 64;
    float acc[4][4] = {};
    for (int k0 = 0; k0 < Ksz; k0 += 16) {
        {   // A tile (transposed store into As[k][m])
            int row = t >> 2, kq = (t & 3) * 4;
            float4 a4 = *(const float4*)&A[(size_t)(m0 + row) * Ksz + k0 + kq];
            As[kq + 0][row] = a4.x; As[kq + 1][row] = a4.y;
            As[kq + 2][row] = a4.z; As[kq + 3][row] = a4.w;
        }
        if (TRANSB) {  // B is [Nn, Ksz] row-major; Bs[k][n] = B[n][k]
            int nrow = t >> 2, kq = (t & 3) * 4;
            float4 b4 = *(const float4*)&B[(size_t)(n0 + nrow) * Ksz + k0 + kq];
            Bs[kq + 0][nrow] = b4.x; Bs[kq + 1][nrow] = b4.y;
            Bs[kq + 2][nrow] = b4.z; Bs[kq + 3][nrow] = b4.w;
        } else {       // B is [Ksz, Nn] row-major
            int krow = t >> 4, cq = (t & 15) * 4;
            float4 b4 = *(const float4*)&B[(size_t)(k0 + krow) * Nn + n0 + cq];
            *(float4*)&Bs[krow][cq] = b4;
        }
        __syncthreads();
#pragma unroll
        for (int kk = 0; kk < 16; kk++) {
            float4 av = *(float4*)&As[kk][ty * 4];
            float4 bv = *(float4*)&Bs[kk][tx * 4];
            float a[4] = {av.x, av.y, av.z, av.w};
            float b[4] = {bv.x, bv.y, bv.z, bv.w};
#pragma unroll
            for (int i = 0; i < 4; i++)
#pragma unroll
                for (int j = 0; j < 4; j++) acc[i][j] += a[i] * b[j];
        }
        __syncthreads();
    }
#pragma unroll
    for (int i = 0; i < 4; i++) {
        int m = m0 + ty * 4 + i;
        int n = n0 + tx * 4;
        float4 o;
        o.x = acc[i][0]; o.y = acc[i][1]; o.z = acc[i][2]; o.w = acc[i][3];
        if (bias) {
            o.x += bias[n + 0]; o.y += bias[n + 1];
            o.z += bias[n + 2]; o.w += bias[n + 3];
        }
        *(float4*)&C[(size_t)m * Nn + n] = o;
    }
}

// ---------------- src/dst projections: srcT[k][n], dstT[k][n] ----------------
__global__ void src_dst_kernel(const float* __restrict__ h,
                               const float* __restrict__ aw,
                               const float* __restrict__ ab,
                               float* __restrict__ srcT, float* __restrict__ dstT) {
    __shared__ __align__(16) float awl[KK * 2 * HH];
    int t = threadIdx.x;
    for (int q = 0; q < 4; q++) {
        int i4 = t + q * 256;
        *(float4*)&awl[i4 * 4] = *(const float4*)&aw[i4 * 4];
    }
    __syncthreads();
    int k = t & 7, nl = t >> 3;
    int n = blockIdx.x * 32 + nl;
    float s = ab[k], d = 0.f;
    const float* hp = &h[(size_t)n * HH];
    const float* ws = &awl[k * 512];
    const float* wd = ws + 256;
    for (int c = 0; c < 256; c++) {
        float hv = hp[c];
        s += hv * ws[c];
        d += hv * wd[c];
    }
    srcT[k * NN + n] = s;
    dstT[k * NN + n] = d;
}

// ---------------- per-head max of dst (softmax upper-bound stabilizer) --------
__global__ void maxdst_kernel(const float* __restrict__ dstT, float* __restrict__ maxd) {
    int k = blockIdx.x, t = threadIdx.x;
    float m = -1e30f;
    for (int i = t; i < NN; i += 256) m = fmaxf(m, dstT[(size_t)k * NN + i]);
    for (int off = 32; off > 0; off >>= 1) m = fmaxf(m, __shfl_down(m, off));
    __shared__ float red[4];
    if ((t & 63) == 0) red[t >> 6] = m;
    __syncthreads();
    if (t == 0) maxd[k] = fmaxf(fmaxf(red[0], red[1]), fmaxf(red[2], red[3]));
}

// ---------------- h fp32 -> HB bf16, pre-swizzled into MFMA B-fragment order --
// HB[jb][nt][lane][jj] = bf16( h[jb*32 + (lane>>4)*8 + jj][nt*16 + (lane&15)] )
__global__ __launch_bounds__(256) void convert_hb_kernel(const float* __restrict__ h,
                                                         bf16x8* __restrict__ HB) {
    __shared__ float hs[32 * 257];
    int t = threadIdx.x, jb = blockIdx.x;
    {
        int r = t >> 3, cb = (t & 7) * 32;
        const float* hp = &h[(size_t)(jb * 32 + r) * HH + cb];
        float* dp = &hs[r * 257 + cb];
#pragma unroll
        for (int q = 0; q < 8; q++) *(float4*)&dp[q * 4] = *(const float4*)&hp[q * 4];
    }
    __syncthreads();
#pragma unroll
    for (int it = 0; it < 4; it++) {
        int id = t + it * 256;
        int nt = id >> 6, lane = id & 63;
        int c = nt * 16 + (lane & 15), j8 = (lane >> 4) * 8;
        bf16x8 v;
#pragma unroll
        for (int jj = 0; jj < 8; jj++) v[jj] = f2bf(hs[(j8 + jj) * 257 + c]);
        HB[(size_t)jb * 1024 + nt * 64 + lane] = v;
    }
}

// ---------------- MFMA attention: 64 rows x 1 head per block, 4 waves --------
// Wave w owns rows i0+w*16..+15, all 256 cols (16 n-tiles). P fragment built in
// registers (A-layout: A[m=lane&15][k=quad*8+jj]); B loaded from pre-swizzled HB.
// Unnormalized p = exp(lrelu(src+dst) - m_i), m_i = lrelu(src_i + maxdst);
// row sums l accumulated in registers, normalized in epilogue.
// MODE 1: out[i][k*HH+c] = elu(h[i][c] + (P@H)/l)   (layer 1, concat)
// MODE 2: out[k][i][c]   = (P@H)/l                  (layer 2 head planes)
template <int MODE>
__global__ __launch_bounds__(256) void attn_mfma_kernel(
    const float* __restrict__ h, const float* __restrict__ srcT,
    const float* __restrict__ dstT, const float* __restrict__ maxd,
    const unsigned int* __restrict__ mbits, const bf16x8* __restrict__ HB,
    float* __restrict__ out) {
    __shared__ __align__(16) float dst_l[NN];       // 16 KB
    __shared__ unsigned int mrow_l[64 * 132];       // 33.8 KB, stride 132: bank-safe

    int t = threadIdx.x;
    int i0 = blockIdx.x * 64;
    int k = blockIdx.y;

    for (int q = 0; q < 4; q++) {
        int i4 = t + q * 256;
        *(float4*)&dst_l[i4 * 4] = *(const float4*)&dstT[(size_t)k * NN + i4 * 4];
    }
    for (int q = 0; q < 32; q++) {
        int idx = t + q * 256;             // 0..8191
        int r = idx >> 7, wd = idx & 127;
        mrow_l[r * 132 + wd] = mbits[(size_t)(i0 + r) * 128 + wd];
    }
    __syncthreads();

    int w = t >> 6, lane = t & 63, quad = lane >> 4, c16 = lane & 15;
    int mrow = w * 16 + c16;  // this lane's P row (block-local)
    float srcv = srcT[(size_t)k * NN + i0 + mrow];
    float mval;
    {
        float x = srcv + maxd[k];
        mval = fmaxf(x, 0.01f * x);  // lrelu: valid upper bound on all row logits
    }
    f32x4 acc[16];
#pragma unroll
    for (int nt = 0; nt < 16; nt++) acc[nt] = (f32x4){0.f, 0.f, 0.f, 0.f};
    float lacc = 0.f;
    const bf16x8* hbp = HB + (size_t)lane;
    int mbase = mrow * 132;

    for (int jb = 0; jb < 128; jb++) {
        unsigned int word = mrow_l[mbase + jb];
        unsigned int mb = (word >> (quad * 8)) & 0xffu;
        const float* dp = &dst_l[jb * 32 + quad * 8];
        float4 d0 = *(const float4*)dp;
        float4 d1 = *(const float4*)(dp + 4);
        float dd[8] = {d0.x, d0.y, d0.z, d0.w, d1.x, d1.y, d1.z, d1.w};
        float p[8];
#pragma unroll
        for (int jj = 0; jj < 8; jj++) {
            float x = srcv + dd[jj];
            float lg = fmaxf(x, 0.01f * x);
            float e = __expf(lg - mval);
            p[jj] = ((mb >> jj) & 1u) ? e : 0.f;
            lacc += p[jj];
        }
        bf16x8 ap;
#pragma unroll
        for (int jj = 0; jj < 8; jj++) ap[jj] = f2bf(p[jj]);
        const bf16x8* bp = hbp + (size_t)jb * 1024;
#pragma unroll
        for (int nt = 0; nt < 16; nt++) {
            bf16x8 bv = bp[nt * 64];
            acc[nt] = __builtin_amdgcn_mfma_f32_16x16x32_bf16(ap, bv, acc[nt], 0, 0, 0);
        }
    }

    // reduce row sums across the 4 quads holding the same row
    lacc += __shfl_xor(lacc, 16);
    lacc += __shfl_xor(lacc, 32);
    float linv = (lacc > 0.f) ? 1.f / lacc : 0.f;  // l==0: isolated row

    // epilogue: C/D layout col=lane&15, row=quad*4+reg
#pragma unroll
    for (int reg = 0; reg < 4; reg++) {
        int rloc = quad * 4 + reg;         // 0..15 within wave's row group
        float li = __shfl(linv, rloc);     // lane rloc holds row rloc's linv
        int i = i0 + w * 16 + rloc;
#pragma unroll
        for (int nt = 0; nt < 16; nt++) {
            float v = acc[nt][reg] * li;
            int c = nt * 16 + c16;
            if (MODE == 1) {
                v += h[(size_t)i * HH + c];
                v = (v > 0.f) ? v : (__expf(v) - 1.f);  // elu
                out[(size_t)i * KH + (size_t)k * HH + c] = v;
            } else {
                out[(size_t)k * NN * HH + (size_t)i * HH + c] = v;
            }
        }
    }
}

// ---------------- elu(avg of heads) column partial sums ----------------
__global__ void colsum_kernel(const float* __restrict__ h2,
                              const float* __restrict__ heads,
                              float* __restrict__ partial) {
    int c = threadIdx.x;
    int b = blockIdx.x;
    float s = 0.f;
    for (int il = 0; il < 64; il++) {
        int i = b * 64 + il;
        float v = h2[(size_t)i * HH + c];
#pragma unroll
        for (int k = 0; k < KK; k++)
            v += 0.125f * heads[(size_t)k * NN * HH + (size_t)i * HH + c];
        s += (v > 0.f) ? v : (__expf(v) - 1.f);
    }
    partial[b * HH + c] = s;
}

__global__ void final_kernel(const float* __restrict__ partial,
                             const float* __restrict__ out_w,
                             const float* __restrict__ out_b,
                             float* __restrict__ dout) {
    __shared__ float red[256];
    int c = threadIdx.x;
    float s = 0.f;
    for (int b = 0; b < 64; b++) s += partial[b * HH + c];
    red[c] = (s / 4096.f) * out_w[c];
    __syncthreads();
    for (int off = 128; off > 0; off >>= 1) {
        if (c < off) red[c] += red[c + off];
        __syncthreads();
    }
    if (c == 0) dout[0] = red[0] + out_b[0];
}

extern "C" void kernel_launch(void* const* d_in, const int* in_sizes, int n_in,
                              void* d_out, int out_size, void* d_ws, size_t ws_size,
                              hipStream_t stream) {
    (void)in_sizes; (void)n_in; (void)out_size; (void)ws_size;
    const float* adj   = (const float*)d_in[0];
    const float* feats = (const float*)d_in[1];
    const float* W1_w  = (const float*)d_in[2];
    const float* W1_b  = (const float*)d_in[3];
    const float* a1_w  = (const float*)d_in[4];
    const float* a1_b  = (const float*)d_in[5];
    const float* W2_w  = (const float*)d_in[6];
    const float* W2_b  = (const float*)d_in[7];
    const float* a2_w  = (const float*)d_in[8];
    const float* a2_b  = (const float*)d_in[9];
    const float* out_w = (const float*)d_in[10];
    const float* out_b = (const float*)d_in[11];

    char* w = (char*)d_ws;
    unsigned int* mbits = (unsigned int*)w;                         // 2 MB
    float* tmp1    = (float*)(w + (2ull  << 20));                   // 8 MB  [N,F] (dead after h1)
    bf16x8* HB     = (bf16x8*)(w + (2ull << 20));                   // 2 MB, reuses tmp1 region
    float* h1      = (float*)(w + (10ull << 20));                   // 4 MB  [N,H]
    float* srcT    = (float*)(w + (14ull << 20));                   // 128 KB [K,N]
    float* dstT    = (float*)(w + (14ull << 20) + (128ull << 10));  // 128 KB
    float* maxd    = (float*)(w + (14ull << 20) + (256ull << 10));  // 32 B
    float* h1n     = (float*)(w + (15ull << 20));                   // 32 MB [N,K*H] (reused as head planes)
    float* h2      = (float*)(w + (47ull << 20));                   // 4 MB  [N,H]
    float* partial = (float*)(w + (51ull << 20));                   // 64 KB

    pack_mask_kernel<<<NN, 256, 0, stream>>>(adj, mbits);
    // tmp1 = A @ feats
    gemm64_kernel<0><<<dim3(FF / 64, NN / 64), 256, 0, stream>>>(
        adj, feats, nullptr, tmp1, NN, FF, NN);
    // h1 = tmp1 @ W1^T + b1
    gemm64_kernel<1><<<dim3(HH / 64, NN / 64), 256, 0, stream>>>(
        tmp1, W1_w, W1_b, h1, NN, HH, FF);
    src_dst_kernel<<<NN / 32, 256, 0, stream>>>(h1, a1_w, a1_b, srcT, dstT);
    maxdst_kernel<<<KK, 256, 0, stream>>>(dstT, maxd);
    convert_hb_kernel<<<NN / 32, 256, 0, stream>>>(h1, HB);  // overwrites tmp1 (consumed)
    // layer-1 attention -> h1n = elu(concat heads)
    attn_mfma_kernel<1><<<dim3(NN / 64, KK), 256, 0, stream>>>(
        h1, srcT, dstT, maxd, mbits, HB, h1n);
    // h2 = h1n @ W2^T + b2
    gemm64_kernel<1><<<dim3(HH / 64, NN / 64), 256, 0, stream>>>(
        h1n, W2_w, W2_b, h2, NN, HH, KH);
    src_dst_kernel<<<NN / 32, 256, 0, stream>>>(h2, a2_w, a2_b, srcT, dstT);
    maxdst_kernel<<<KK, 256, 0, stream>>>(dstT, maxd);
    convert_hb_kernel<<<NN / 32, 256, 0, stream>>>(h2, HB);
    // layer-2 attention -> per-head planes
    attn_mfma_kernel<2><<<dim3(NN / 64, KK), 256, 0, stream>>>(
        h2, srcT, dstT, maxd, mbits, HB, h1n);
    colsum_kernel<<<64, 256, 0, stream>>>(h2, h1n, partial);
    final_kernel<<<1, 256, 0, stream>>>(partial, out_w, out_b, (float*)d_out);
}

// Round 3
// 653.779 us; speedup vs baseline: 8.9942x; 1.2990x over previous
//
#include <hip/hip_runtime.h>
#include <hip/hip_bf16.h>

// GAT round 2: all GEMMs -> bf16 MFMA (fragment-direct, no-LDS), fused mask pack,
// attn layer-1 writes bf16. Attention kernel otherwise unchanged from round 1.

#define NN 4096
#define FF 512
#define HH 256
#define KK 8
#define KH 2048  // KK*HH

typedef __attribute__((ext_vector_type(8))) short bf16x8;
typedef __attribute__((ext_vector_type(4))) float f32x4;

__device__ inline short f2bf(float x) {
    __hip_bfloat16 b = __float2bfloat16(x);
    return *reinterpret_cast<short*>(&b);
}
__device__ inline short to_bf(float x) { return f2bf(x); }
__device__ inline short to_bf(short x) { return x; }

// ---- adjacency: fp32 -> A-frag bf16 (exact) + mask bitpack, single 64MB read ----
// Afrag[mt][kt][lane][jj] = adj[mt*16 + (lane&15)][kt*32 + (lane>>4)*8 + jj]
__global__ __launch_bounds__(256) void cvt_adj_kernel(const float* __restrict__ adj,
                                                      bf16x8* __restrict__ Af,
                                                      unsigned int* __restrict__ mbits) {
    int t = threadIdx.x, lane = t & 63, w = t >> 6, mt = blockIdx.x;
    int m = mt * 16 + (lane & 15), kq = (lane >> 4) * 8;
    for (int kt = w; kt < 128; kt += 4) {
        size_t base = (size_t)m * NN + kt * 32 + kq;
        float4 f0 = *(const float4*)&adj[base];
        float4 f1 = *(const float4*)&adj[base + 4];
        bf16x8 v;
        v[0] = f2bf(f0.x); v[1] = f2bf(f0.y); v[2] = f2bf(f0.z); v[3] = f2bf(f0.w);
        v[4] = f2bf(f1.x); v[5] = f2bf(f1.y); v[6] = f2bf(f1.z); v[7] = f2bf(f1.w);
        Af[((size_t)mt * 128 + kt) * 64 + lane] = v;
    }
    for (int r = w; r < 16; r += 4) {
        int row = mt * 16 + r;
        for (int j0 = 0; j0 < NN; j0 += 64) {
            float vv = adj[(size_t)row * NN + j0 + lane];
            unsigned long long b = __ballot(vv == 1.0f);
            if (lane == 0) {
                mbits[row * 128 + (j0 >> 5)]     = (unsigned int)(b & 0xffffffffull);
                mbits[row * 128 + (j0 >> 5) + 1] = (unsigned int)(b >> 32);
            }
        }
    }
}

// ---- row-major [M][K] (fp32 or bf16 bits) -> A-frag bf16 ----
template <typename T>
__global__ __launch_bounds__(256) void cvt_a_frag_kernel(const T* __restrict__ src,
                                                         bf16x8* __restrict__ dst, int K) {
    int t = threadIdx.x, lane = t & 63, w = t >> 6, mt = blockIdx.x;
    int Kt = K >> 5;
    int m = mt * 16 + (lane & 15), kq = (lane >> 4) * 8;
    for (int kt = w; kt < Kt; kt += 4) {
        size_t base = (size_t)m * K + kt * 32 + kq;
        bf16x8 v;
#pragma unroll
        for (int jj = 0; jj < 8; jj++) v[jj] = to_bf(src[base + jj]);
        dst[((size_t)mt * Kt + kt) * 64 + lane] = v;
    }
}

// ---- W [N][K] row-major (i.e. B^T) fp32 -> B-frag bf16 ----
// Bfrag[kt][nt][lane][jj] = W[nt*16 + (lane&15)][kt*32 + (lane>>4)*8 + jj]
__global__ __launch_bounds__(256) void cvt_bt_frag_kernel(const float* __restrict__ Wm,
                                                          bf16x8* __restrict__ dst,
                                                          int K, int Nt) {
    int t = threadIdx.x, lane = t & 63, w = t >> 6, nt = blockIdx.x;
    int Kt = K >> 5;
    int n = nt * 16 + (lane & 15), kq = (lane >> 4) * 8;
    for (int kt = w; kt < Kt; kt += 4) {
        size_t base = (size_t)n * K + kt * 32 + kq;
        bf16x8 v;
#pragma unroll
        for (int jj = 0; jj < 8; jj++) v[jj] = f2bf(Wm[base + jj]);
        dst[((size_t)kt * Nt + nt) * 64 + lane] = v;
    }
}

// ---- src [K][W] fp32 -> B-frag bf16 (LDS-staged transpose) ----
// Bfrag[kt][nt][lane][jj] = src[kt*32 + (lane>>4)*8 + jj][nt*16 + (lane&15)]
template <int W>
__global__ __launch_bounds__(256) void cvt_b_frag_kernel(const float* __restrict__ src,
                                                         bf16x8* __restrict__ dst) {
    __shared__ float hs[32][W + 8];
    constexpr int Nt = W / 16;
    int t = threadIdx.x, jb = blockIdx.x;
    {
        int r = t >> 3, cb = (t & 7) * (W / 8);
        const float* sp = &src[(size_t)(jb * 32 + r) * W + cb];
#pragma unroll
        for (int q = 0; q < W / 32; q++) *(float4*)&hs[r][cb + q * 4] = *(const float4*)&sp[q * 4];
    }
    __syncthreads();
    for (int id = t; id < Nt * 64; id += 256) {
        int nt = id >> 6, lane = id & 63;
        int c = nt * 16 + (lane & 15), q8 = (lane >> 4) * 8;
        bf16x8 v;
#pragma unroll
        for (int jj = 0; jj < 8; jj++) v[jj] = f2bf(hs[q8 + jj][c]);
        dst[((size_t)jb * Nt + nt) * 64 + lane] = v;
    }
}

// ---- fragment-direct bf16 MFMA GEMM: C[m][n] fp32 = A@B (+bias) ----
// Block: 64 rows x 128 cols, 4 waves (wave: 2 mtiles x 4 ntiles). No LDS.
__global__ __launch_bounds__(256) void gemm_frag_kernel(
    const bf16x8* __restrict__ Af, const bf16x8* __restrict__ Bf,
    const float* __restrict__ bias, float* __restrict__ C,
    int Kt, int Nt, int Nrow) {
    int t = threadIdx.x, lane = t & 63, w = t >> 6;
    int quad = lane >> 4, c16 = lane & 15;
    int wm = w & 1, wn = w >> 1;
    int mt0 = blockIdx.y * 4 + wm * 2;
    int nt0 = blockIdx.x * 8 + wn * 4;
    f32x4 acc[2][4];
#pragma unroll
    for (int i = 0; i < 2; i++)
#pragma unroll
        for (int j = 0; j < 4; j++) acc[i][j] = (f32x4){0.f, 0.f, 0.f, 0.f};
    const bf16x8* ap = Af + (size_t)mt0 * Kt * 64 + lane;
    const bf16x8* bp = Bf + (size_t)nt0 * 64 + lane;
#pragma unroll 2
    for (int kt = 0; kt < Kt; kt++) {
        bf16x8 a0 = ap[(size_t)kt * 64];
        bf16x8 a1 = ap[((size_t)Kt + kt) * 64];
        bf16x8 b0 = bp[(size_t)kt * Nt * 64];
        bf16x8 b1 = bp[((size_t)kt * Nt + 1) * 64];
        bf16x8 b2 = bp[((size_t)kt * Nt + 2) * 64];
        bf16x8 b3 = bp[((size_t)kt * Nt + 3) * 64];
        acc[0][0] = __builtin_amdgcn_mfma_f32_16x16x32_bf16(a0, b0, acc[0][0], 0, 0, 0);
        acc[0][1] = __builtin_amdgcn_mfma_f32_16x16x32_bf16(a0, b1, acc[0][1], 0, 0, 0);
        acc[0][2] = __builtin_amdgcn_mfma_f32_16x16x32_bf16(a0, b2, acc[0][2], 0, 0, 0);
        acc[0][3] = __builtin_amdgcn_mfma_f32_16x16x32_bf16(a0, b3, acc[0][3], 0, 0, 0);
        acc[1][0] = __builtin_amdgcn_mfma_f32_16x16x32_bf16(a1, b0, acc[1][0], 0, 0, 0);
        acc[1][1] = __builtin_amdgcn_mfma_f32_16x16x32_bf16(a1, b1, acc[1][1], 0, 0, 0);
        acc[1][2] = __builtin_amdgcn_mfma_f32_16x16x32_bf16(a1, b2, acc[1][2], 0, 0, 0);
        acc[1][3] = __builtin_amdgcn_mfma_f32_16x16x32_bf16(a1, b3, acc[1][3], 0, 0, 0);
    }
#pragma unroll
    for (int i = 0; i < 2; i++) {
#pragma unroll
        for (int j = 0; j < 4; j++) {
            int n = (nt0 + j) * 16 + c16;
            float bv = bias ? bias[n] : 0.f;
#pragma unroll
            for (int reg = 0; reg < 4; reg++) {
                int m = (mt0 + i) * 16 + quad * 4 + reg;
                C[(size_t)m * Nrow + n] = acc[i][j][reg] + bv;
            }
        }
    }
}

// ---------------- src/dst projections: srcT[k][n], dstT[k][n] ----------------
__global__ void src_dst_kernel(const float* __restrict__ h,
                               const float* __restrict__ aw,
                               const float* __restrict__ ab,
                               float* __restrict__ srcT, float* __restrict__ dstT) {
    __shared__ __align__(16) float awl[KK * 2 * HH];
    int t = threadIdx.x;
    for (int q = 0; q < 4; q++) {
        int i4 = t + q * 256;
        *(float4*)&awl[i4 * 4] = *(const float4*)&aw[i4 * 4];
    }
    __syncthreads();
    int k = t & 7, nl = t >> 3;
    int n = blockIdx.x * 32 + nl;
    float s = ab[k], d = 0.f;
    const float* hp = &h[(size_t)n * HH];
    const float* ws = &awl[k * 512];
    const float* wd = ws + 256;
    for (int c = 0; c < 256; c += 4) {
        float4 hv = *(const float4*)&hp[c];
        float4 wsv = *(const float4*)&ws[c];
        float4 wdv = *(const float4*)&wd[c];
        s += hv.x * wsv.x + hv.y * wsv.y + hv.z * wsv.z + hv.w * wsv.w;
        d += hv.x * wdv.x + hv.y * wdv.y + hv.z * wdv.z + hv.w * wdv.w;
    }
    srcT[k * NN + n] = s;
    dstT[k * NN + n] = d;
}

// ---------------- per-head max of dst (softmax upper-bound stabilizer) --------
__global__ void maxdst_kernel(const float* __restrict__ dstT, float* __restrict__ maxd) {
    int k = blockIdx.x, t = threadIdx.x;
    float m = -1e30f;
    for (int i = t; i < NN; i += 256) m = fmaxf(m, dstT[(size_t)k * NN + i]);
    for (int off = 32; off > 0; off >>= 1) m = fmaxf(m, __shfl_down(m, off));
    __shared__ float red[4];
    if ((t & 63) == 0) red[t >> 6] = m;
    __syncthreads();
    if (t == 0) maxd[k] = fmaxf(fmaxf(red[0], red[1]), fmaxf(red[2], red[3]));
}

// ---------------- MFMA attention (as round 1; MODE 1 now writes bf16) --------
// MODE 1: outb[i][k*HH+c] = bf16(elu(h[i][c] + (P@H)/l))
// MODE 2: outf[k][i][c]   = (P@H)/l
template <int MODE>
__global__ __launch_bounds__(256) void attn_mfma_kernel(
    const float* __restrict__ h, const float* __restrict__ srcT,
    const float* __restrict__ dstT, const float* __restrict__ maxd,
    const unsigned int* __restrict__ mbits, const bf16x8* __restrict__ HB,
    void* __restrict__ outp) {
    __shared__ __align__(16) float dst_l[NN];
    __shared__ unsigned int mrow_l[64 * 132];

    int t = threadIdx.x;
    int i0 = blockIdx.x * 64;
    int k = blockIdx.y;

    for (int q = 0; q < 4; q++) {
        int i4 = t + q * 256;
        *(float4*)&dst_l[i4 * 4] = *(const float4*)&dstT[(size_t)k * NN + i4 * 4];
    }
    for (int q = 0; q < 32; q++) {
        int idx = t + q * 256;
        int r = idx >> 7, wd = idx & 127;
        mrow_l[r * 132 + wd] = mbits[(size_t)(i0 + r) * 128 + wd];
    }
    __syncthreads();

    int w = t >> 6, lane = t & 63, quad = lane >> 4, c16 = lane & 15;
    int mrow = w * 16 + c16;
    float srcv = srcT[(size_t)k * NN + i0 + mrow];
    float mval;
    {
        float x = srcv + maxd[k];
        mval = fmaxf(x, 0.01f * x);
    }
    f32x4 acc[16];
#pragma unroll
    for (int nt = 0; nt < 16; nt++) acc[nt] = (f32x4){0.f, 0.f, 0.f, 0.f};
    float lacc = 0.f;
    const bf16x8* hbp = HB + (size_t)lane;
    int mbase = mrow * 132;

    for (int jb = 0; jb < 128; jb++) {
        unsigned int word = mrow_l[mbase + jb];
        unsigned int mb = (word >> (quad * 8)) & 0xffu;
        const float* dp = &dst_l[jb * 32 + quad * 8];
        float4 d0 = *(const float4*)dp;
        float4 d1 = *(const float4*)(dp + 4);
        float dd[8] = {d0.x, d0.y, d0.z, d0.w, d1.x, d1.y, d1.z, d1.w};
        float p[8];
#pragma unroll
        for (int jj = 0; jj < 8; jj++) {
            float x = srcv + dd[jj];
            float lg = fmaxf(x, 0.01f * x);
            float e = __expf(lg - mval);
            p[jj] = ((mb >> jj) & 1u) ? e : 0.f;
            lacc += p[jj];
        }
        bf16x8 ap;
#pragma unroll
        for (int jj = 0; jj < 8; jj++) ap[jj] = f2bf(p[jj]);
        const bf16x8* bp = hbp + (size_t)jb * 1024;
#pragma unroll
        for (int nt = 0; nt < 16; nt++) {
            bf16x8 bv = bp[nt * 64];
            acc[nt] = __builtin_amdgcn_mfma_f32_16x16x32_bf16(ap, bv, acc[nt], 0, 0, 0);
        }
    }

    lacc += __shfl_xor(lacc, 16);
    lacc += __shfl_xor(lacc, 32);
    float linv = (lacc > 0.f) ? 1.f / lacc : 0.f;

#pragma unroll
    for (int reg = 0; reg < 4; reg++) {
        int rloc = quad * 4 + reg;
        float li = __shfl(linv, rloc);
        int i = i0 + w * 16 + rloc;
#pragma unroll
        for (int nt = 0; nt < 16; nt++) {
            float v = acc[nt][reg] * li;
            int c = nt * 16 + c16;
            if (MODE == 1) {
                v += h[(size_t)i * HH + c];
                v = (v > 0.f) ? v : (__expf(v) - 1.f);  // elu
                ((short*)outp)[(size_t)i * KH + (size_t)k * HH + c] = f2bf(v);
            } else {
                ((float*)outp)[(size_t)k * NN * HH + (size_t)i * HH + c] = v;
            }
        }
    }
}

// ---------------- elu(avg of heads) column partial sums ----------------
__global__ void colsum_kernel(const float* __restrict__ h2,
                              const float* __restrict__ heads,
                              float* __restrict__ partial) {
    int c = threadIdx.x;
    int b = blockIdx.x;
    float s = 0.f;
    for (int il = 0; il < 64; il++) {
        int i = b * 64 + il;
        float v = h2[(size_t)i * HH + c];
#pragma unroll
        for (int k = 0; k < KK; k++)
            v += 0.125f * heads[(size_t)k * NN * HH + (size_t)i * HH + c];
        s += (v > 0.f) ? v : (__expf(v) - 1.f);
    }
    partial[b * HH + c] = s;
}

__global__ void final_kernel(const float* __restrict__ partial,
                             const float* __restrict__ out_w,
                             const float* __restrict__ out_b,
                             float* __restrict__ dout) {
    __shared__ float red[256];
    int c = threadIdx.x;
    float s = 0.f;
    for (int b = 0; b < 64; b++) s += partial[b * HH + c];
    red[c] = (s / 4096.f) * out_w[c];
    __syncthreads();
    for (int off = 128; off > 0; off >>= 1) {
        if (c < off) red[c] += red[c + off];
        __syncthreads();
    }
    if (c == 0) dout[0] = red[0] + out_b[0];
}

extern "C" void kernel_launch(void* const* d_in, const int* in_sizes, int n_in,
                              void* d_out, int out_size, void* d_ws, size_t ws_size,
                              hipStream_t stream) {
    (void)in_sizes; (void)n_in; (void)out_size; (void)ws_size;
    const float* adj   = (const float*)d_in[0];
    const float* feats = (const float*)d_in[1];
    const float* W1_w  = (const float*)d_in[2];
    const float* W1_b  = (const float*)d_in[3];
    const float* a1_w  = (const float*)d_in[4];
    const float* a1_b  = (const float*)d_in[5];
    const float* W2_w  = (const float*)d_in[6];
    const float* W2_b  = (const float*)d_in[7];
    const float* a2_w  = (const float*)d_in[8];
    const float* a2_b  = (const float*)d_in[9];
    const float* out_w = (const float*)d_in[10];
    const float* out_b = (const float*)d_in[11];

    char* w = (char*)d_ws;
    const size_t MB = 1ull << 20;
    // Phase-overlapped workspace layout (total ~50.1 MB):
    unsigned int* mbits = (unsigned int*)(w);            // 0..2MB
    bf16x8* Aadj   = (bf16x8*)(w + 2 * MB);              // 2..34MB   (phase 1)
    short*  h1nb   = (short*)(w + 2 * MB);               // 2..18MB   (phase 2: attn1 out, bf16)
    bf16x8* h1na   = (bf16x8*)(w + 18 * MB);             // 18..34MB  (phase 2: A-frag)
    float*  planes = (float*)(w + 2 * MB);               // 2..34MB   (phase 3: attn2 heads)
    bf16x8* Bfeats = (bf16x8*)(w + 34 * MB);             // 34..38MB  (phase 1)
    float*  h2     = (float*)(w + 34 * MB);              // 34..38MB  (phase 3)
    float*  tmp1   = (float*)(w + 38 * MB);              // 38..46MB  (phase 1)
    float*  h1     = (float*)(w + 38 * MB);              // 38..42MB  (phase 2; tmp1 dead)
    bf16x8* W1f    = (bf16x8*)(w + 42 * MB);             // 42..42.25MB
    bf16x8* W2f    = (bf16x8*)(w + 42 * MB + 256 * 1024);  // 42.25..43.25MB
    float*  srcT   = (float*)(w + 43 * MB + 256 * 1024);   // 128 KB
    float*  dstT   = (float*)(w + 43 * MB + 384 * 1024);   // 128 KB
    float*  maxd   = (float*)(w + 43 * MB + 512 * 1024);   // tiny
    bf16x8* HB     = (bf16x8*)(w + 44 * MB);             // 44..46MB
    bf16x8* tmp1a  = (bf16x8*)(w + 46 * MB);             // 46..50MB
    float*  partial = (float*)(w + 50 * MB);             // 64 KB

    // --- phase 1: h1 = (A @ feats) @ W1^T + b1, all bf16 MFMA ---
    cvt_adj_kernel<<<NN / 16, 256, 0, stream>>>(adj, Aadj, mbits);
    cvt_b_frag_kernel<FF><<<NN / 32, 256, 0, stream>>>(feats, Bfeats);
    gemm_frag_kernel<<<dim3(FF / 128, NN / 64), 256, 0, stream>>>(
        Aadj, Bfeats, nullptr, tmp1, NN / 32, FF / 16, FF);
    cvt_a_frag_kernel<float><<<NN / 16, 256, 0, stream>>>(tmp1, tmp1a, FF);
    cvt_bt_frag_kernel<<<HH / 16, 256, 0, stream>>>(W1_w, W1f, FF, HH / 16);
    gemm_frag_kernel<<<dim3(HH / 128, NN / 64), 256, 0, stream>>>(
        tmp1a, W1f, W1_b, h1, FF / 32, HH / 16, HH);

    // --- phase 2: layer-1 attention -> h1nb (bf16), then h2 ---
    src_dst_kernel<<<NN / 32, 256, 0, stream>>>(h1, a1_w, a1_b, srcT, dstT);
    maxdst_kernel<<<KK, 256, 0, stream>>>(dstT, maxd);
    cvt_b_frag_kernel<HH><<<NN / 32, 256, 0, stream>>>(h1, HB);
    attn_mfma_kernel<1><<<dim3(NN / 64, KK), 256, 0, stream>>>(
        h1, srcT, dstT, maxd, mbits, HB, h1nb);
    cvt_a_frag_kernel<short><<<NN / 16, 256, 0, stream>>>(h1nb, h1na, KH);
    cvt_bt_frag_kernel<<<HH / 16, 256, 0, stream>>>(W2_w, W2f, KH, HH / 16);
    gemm_frag_kernel<<<dim3(HH / 128, NN / 64), 256, 0, stream>>>(
        h1na, W2f, W2_b, h2, KH / 32, HH / 16, HH);

    // --- phase 3: layer-2 attention -> head planes, reduce ---
    src_dst_kernel<<<NN / 32, 256, 0, stream>>>(h2, a2_w, a2_b, srcT, dstT);
    maxdst_kernel<<<KK, 256, 0, stream>>>(dstT, maxd);
    cvt_b_frag_kernel<HH><<<NN / 32, 256, 0, stream>>>(h2, HB);
    attn_mfma_kernel<2><<<dim3(NN / 64, KK), 256, 0, stream>>>(
        h2, srcT, dstT, maxd, mbits, HB, planes);
    colsum_kernel<<<64, 256, 0, stream>>>(h2, planes, partial);
    final_kernel<<<1, 256, 0, stream>>>(partial, out_w, out_b, (float*)d_out);
}

// Round 4
// 539.041 us; speedup vs baseline: 10.9087x; 1.2129x over previous
//
#include <hip/hip_runtime.h>
#include <hip/hip_bf16.h>

// GAT round 3: attention -> 32x32x16 MFMA, 2 heads/wave (4x less L2 B-traffic),
// j-split waves for 2 waves/SIMD, exp2-domain softmax, v_perm bf16 packing.
// prep_kernel fuses src/dst projection + B-swizzle emission.

#define NN 4096
#define FF 512
#define HH 256
#define KK 8
#define KH 2048  // KK*HH

typedef __attribute__((ext_vector_type(8))) short bf16x8;
typedef __attribute__((ext_vector_type(4))) float f32x4;
typedef __attribute__((ext_vector_type(16))) float f32x16;

__device__ inline short f2bf(float x) {
    __hip_bfloat16 b = __float2bfloat16(x);
    return *reinterpret_cast<short*>(&b);
}
__device__ inline short to_bf(float x) { return f2bf(x); }
__device__ inline short to_bf(short x) { return x; }

// ---- adjacency: fp32 -> A-frag bf16 (exact) + mask bitpack, single 64MB read ----
__global__ __launch_bounds__(256) void cvt_adj_kernel(const float* __restrict__ adj,
                                                      bf16x8* __restrict__ Af,
                                                      unsigned int* __restrict__ mbits) {
    int t = threadIdx.x, lane = t & 63, w = t >> 6, mt = blockIdx.x;
    int m = mt * 16 + (lane & 15), kq = (lane >> 4) * 8;
    for (int kt = w; kt < 128; kt += 4) {
        size_t base = (size_t)m * NN + kt * 32 + kq;
        float4 f0 = *(const float4*)&adj[base];
        float4 f1 = *(const float4*)&adj[base + 4];
        bf16x8 v;
        v[0] = f2bf(f0.x); v[1] = f2bf(f0.y); v[2] = f2bf(f0.z); v[3] = f2bf(f0.w);
        v[4] = f2bf(f1.x); v[5] = f2bf(f1.y); v[6] = f2bf(f1.z); v[7] = f2bf(f1.w);
        Af[((size_t)mt * 128 + kt) * 64 + lane] = v;
    }
    for (int r = w; r < 16; r += 4) {
        int row = mt * 16 + r;
        for (int j0 = 0; j0 < NN; j0 += 64) {
            float vv = adj[(size_t)row * NN + j0 + lane];
            unsigned long long b = __ballot(vv == 1.0f);
            if (lane == 0) {
                mbits[row * 128 + (j0 >> 5)]     = (unsigned int)(b & 0xffffffffull);
                mbits[row * 128 + (j0 >> 5) + 1] = (unsigned int)(b >> 32);
            }
        }
    }
}

// ---- row-major [M][K] (fp32 or bf16 bits) -> A-frag bf16 (16x16x32 layout) ----
template <typename T>
__global__ __launch_bounds__(256) void cvt_a_frag_kernel(const T* __restrict__ src,
                                                         bf16x8* __restrict__ dst, int K) {
    int t = threadIdx.x, lane = t & 63, w = t >> 6, mt = blockIdx.x;
    int Kt = K >> 5;
    int m = mt * 16 + (lane & 15), kq = (lane >> 4) * 8;
    for (int kt = w; kt < Kt; kt += 4) {
        size_t base = (size_t)m * K + kt * 32 + kq;
        bf16x8 v;
#pragma unroll
        for (int jj = 0; jj < 8; jj++) v[jj] = to_bf(src[base + jj]);
        dst[((size_t)mt * Kt + kt) * 64 + lane] = v;
    }
}

// ---- W [N][K] row-major (B^T) fp32 -> B-frag bf16 ----
__global__ __launch_bounds__(256) void cvt_bt_frag_kernel(const float* __restrict__ Wm,
                                                          bf16x8* __restrict__ dst,
                                                          int K, int Nt) {
    int t = threadIdx.x, lane = t & 63, w = t >> 6, nt = blockIdx.x;
    int Kt = K >> 5;
    int n = nt * 16 + (lane & 15), kq = (lane >> 4) * 8;
    for (int kt = w; kt < Kt; kt += 4) {
        size_t base = (size_t)n * K + kt * 32 + kq;
        bf16x8 v;
#pragma unroll
        for (int jj = 0; jj < 8; jj++) v[jj] = f2bf(Wm[base + jj]);
        dst[((size_t)kt * Nt + nt) * 64 + lane] = v;
    }
}

// ---- src [K][W] fp32 -> B-frag bf16 (16x16x32 layout, LDS-staged) ----
template <int W>
__global__ __launch_bounds__(256) void cvt_b_frag_kernel(const float* __restrict__ src,
                                                         bf16x8* __restrict__ dst) {
    __shared__ float hs[32][W + 8];
    constexpr int Nt = W / 16;
    int t = threadIdx.x, jb = blockIdx.x;
    {
        int r = t >> 3, cb = (t & 7) * (W / 8);
        const float* sp = &src[(size_t)(jb * 32 + r) * W + cb];
#pragma unroll
        for (int q = 0; q < W / 32; q++) *(float4*)&hs[r][cb + q * 4] = *(const float4*)&sp[q * 4];
    }
    __syncthreads();
    for (int id = t; id < Nt * 64; id += 256) {
        int nt = id >> 6, lane = id & 63;
        int c = nt * 16 + (lane & 15), q8 = (lane >> 4) * 8;
        bf16x8 v;
#pragma unroll
        for (int jj = 0; jj < 8; jj++) v[jj] = f2bf(hs[q8 + jj][c]);
        dst[((size_t)jb * Nt + nt) * 64 + lane] = v;
    }
}

// ---- fragment-direct bf16 MFMA GEMM (16x16x32): C = A@B (+bias) ----
__global__ __launch_bounds__(256) void gemm_frag_kernel(
    const bf16x8* __restrict__ Af, const bf16x8* __restrict__ Bf,
    const float* __restrict__ bias, float* __restrict__ C,
    int Kt, int Nt, int Nrow) {
    int t = threadIdx.x, lane = t & 63, w = t >> 6;
    int quad = lane >> 4, c16 = lane & 15;
    int wm = w & 1, wn = w >> 1;
    int mt0 = blockIdx.y * 4 + wm * 2;
    int nt0 = blockIdx.x * 8 + wn * 4;
    f32x4 acc[2][4];
#pragma unroll
    for (int i = 0; i < 2; i++)
#pragma unroll
        for (int j = 0; j < 4; j++) acc[i][j] = (f32x4){0.f, 0.f, 0.f, 0.f};
    const bf16x8* ap = Af + (size_t)mt0 * Kt * 64 + lane;
    const bf16x8* bp = Bf + (size_t)nt0 * 64 + lane;
#pragma unroll 2
    for (int kt = 0; kt < Kt; kt++) {
        bf16x8 a0 = ap[(size_t)kt * 64];
        bf16x8 a1 = ap[((size_t)Kt + kt) * 64];
        bf16x8 b0 = bp[(size_t)kt * Nt * 64];
        bf16x8 b1 = bp[((size_t)kt * Nt + 1) * 64];
        bf16x8 b2 = bp[((size_t)kt * Nt + 2) * 64];
        bf16x8 b3 = bp[((size_t)kt * Nt + 3) * 64];
        acc[0][0] = __builtin_amdgcn_mfma_f32_16x16x32_bf16(a0, b0, acc[0][0], 0, 0, 0);
        acc[0][1] = __builtin_amdgcn_mfma_f32_16x16x32_bf16(a0, b1, acc[0][1], 0, 0, 0);
        acc[0][2] = __builtin_amdgcn_mfma_f32_16x16x32_bf16(a0, b2, acc[0][2], 0, 0, 0);
        acc[0][3] = __builtin_amdgcn_mfma_f32_16x16x32_bf16(a0, b3, acc[0][3], 0, 0, 0);
        acc[1][0] = __builtin_amdgcn_mfma_f32_16x16x32_bf16(a1, b0, acc[1][0], 0, 0, 0);
        acc[1][1] = __builtin_amdgcn_mfma_f32_16x16x32_bf16(a1, b1, acc[1][1], 0, 0, 0);
        acc[1][2] = __builtin_amdgcn_mfma_f32_16x16x32_bf16(a1, b2, acc[1][2], 0, 0, 0);
        acc[1][3] = __builtin_amdgcn_mfma_f32_16x16x32_bf16(a1, b3, acc[1][3], 0, 0, 0);
    }
#pragma unroll
    for (int i = 0; i < 2; i++) {
#pragma unroll
        for (int j = 0; j < 4; j++) {
            int n = (nt0 + j) * 16 + c16;
            float bv = bias ? bias[n] : 0.f;
#pragma unroll
            for (int reg = 0; reg < 4; reg++) {
                int m = (mt0 + i) * 16 + quad * 4 + reg;
                C[(size_t)m * Nrow + n] = acc[i][j][reg] + bv;
            }
        }
    }
}

// ---- prep: h -> HB32 (32x32x16 B-frag order) + srcT/dstT (log2e-scaled) ----
// HB32[j16][nt][lane][jj] = bf16( h[j16*16 + (lane>>5)*8 + jj][nt*32 + (lane&31)] )
__global__ __launch_bounds__(256) void prep_kernel(const float* __restrict__ h,
                                                   const float* __restrict__ aw,
                                                   const float* __restrict__ ab,
                                                   bf16x8* __restrict__ HB32,
                                                   float* __restrict__ srcT,
                                                   float* __restrict__ dstT) {
    __shared__ __align__(16) float hs[32][264];
    __shared__ __align__(16) float awl[KK * 512];
    int t = threadIdx.x, jb = blockIdx.x;
#pragma unroll
    for (int q = 0; q < 4; q++)
        *(float4*)&awl[(t + q * 256) * 4] = *(const float4*)&aw[(t + q * 256) * 4];
    {
        int r = t >> 3, cb = (t & 7) * 32;
        const float* hp = &h[(size_t)(jb * 32 + r) * HH + cb];
#pragma unroll
        for (int q = 0; q < 8; q++) *(float4*)&hs[r][cb + q * 4] = *(const float4*)&hp[q * 4];
    }
    __syncthreads();
#pragma unroll
    for (int it = 0; it < 4; it++) {
        int id = t + it * 256;
        int q = id >> 9, nt = (id >> 6) & 7, lane = id & 63;
        int c = nt * 32 + (lane & 31), j8 = q * 16 + (lane >> 5) * 8;
        bf16x8 v;
#pragma unroll
        for (int jj = 0; jj < 8; jj++) v[jj] = f2bf(hs[j8 + jj][c]);
        HB32[((size_t)(jb * 2 + q)) * 512 + nt * 64 + lane] = v;
    }
    {
        const float LOG2E = 1.4426950408889634f;
        int row = t & 31, head = t >> 5;
        float s = ab[head], d = 0.f;
        const float* ws = &awl[head * 512];
        const float* wd = ws + 256;
#pragma unroll 4
        for (int c = 0; c < 256; c += 4) {
            float4 hv = *(const float4*)&hs[row][c];
            float4 a4 = *(const float4*)&ws[c];
            float4 b4 = *(const float4*)&wd[c];
            s += hv.x * a4.x + hv.y * a4.y + hv.z * a4.z + hv.w * a4.w;
            d += hv.x * b4.x + hv.y * b4.y + hv.z * b4.z + hv.w * b4.w;
        }
        srcT[head * NN + jb * 32 + row] = s * LOG2E;
        dstT[head * NN + jb * 32 + row] = d * LOG2E;
    }
}

// ---------------- per-head max of dst (scaled domain) ----------------
__global__ void maxdst_kernel(const float* __restrict__ dstT, float* __restrict__ maxd) {
    int k = blockIdx.x, t = threadIdx.x;
    float m = -1e30f;
    for (int i = t; i < NN; i += 256) m = fmaxf(m, dstT[(size_t)k * NN + i]);
    for (int off = 32; off > 0; off >>= 1) m = fmaxf(m, __shfl_down(m, off));
    __shared__ float red[4];
    if ((t & 63) == 0) red[t >> 6] = m;
    __syncthreads();
    if (t == 0) maxd[k] = fmaxf(fmaxf(red[0], red[1]), fmaxf(red[2], red[3]));
}

// ---- attention, 32x32x16 MFMA: block = 32 rows x 2 heads, 4 waves -----------
// wave w: jh=w&1 (j-half 0..63 / 64..127), ch=w>>1 (cols ch*128..+127)
// Each wave: 2 heads x 4 ntiles acc (128 VGPRs). B loaded once per 2 heads.
// Epilogue merges j-halves via LDS. exp2-domain: srcT/dstT/maxd pre-scaled.
template <int MODE>
__global__ __launch_bounds__(256, 2) void attn32_kernel(
    const float* __restrict__ h, const float* __restrict__ srcT,
    const float* __restrict__ dstT, const float* __restrict__ maxd,
    const unsigned int* __restrict__ mbits, const bf16x8* __restrict__ HB32,
    void* __restrict__ outp) {
    __shared__ __align__(16) char smraw[65536];
    __shared__ float l_all[2][2][32];
    __shared__ float linv_l[2][32];
    float* dstL = (float*)smraw;                          // [2][4096] (loop phase)
    unsigned int* mrow = (unsigned int*)(smraw + 32768);  // [32*131]  (loop phase)
    float* accbuf = (float*)smraw;                        // [2ch][2h][4nt][16reg][64] (epi)

    int t = threadIdx.x;
    int i0 = blockIdx.x * 32;
    int k0 = blockIdx.y * 2;

#pragma unroll
    for (int q = 0; q < 8; q++) {
        int idx = t + q * 256;                // 0..2047 -> float4 units
        int hh = idx >> 10, off = (idx & 1023) * 4;
        *(float4*)&dstL[hh * 4096 + off] = *(const float4*)&dstT[(size_t)(k0 + hh) * NN + off];
    }
#pragma unroll
    for (int q = 0; q < 16; q++) {
        int idx = t + q * 256;                // 0..4095
        int r = idx >> 7, wd = idx & 127;
        mrow[r * 131 + wd] = mbits[(size_t)(i0 + r) * 128 + wd];
    }
    __syncthreads();

    int lane = t & 63, w = t >> 6;
    int jh = w & 1, ch = w >> 1;
    int rowl = lane & 31, jsub = (lane >> 5) * 8;

    float a[2], b[2], lacc[2] = {0.f, 0.f};
#pragma unroll
    for (int hh = 0; hh < 2; hh++) {
        float sL = srcT[(size_t)(k0 + hh) * NN + i0 + rowl];
        float xm = sL + maxd[k0 + hh];
        float mL = fmaxf(xm, 0.01f * xm);     // lrelu upper bound (scaled domain)
        a[hh] = sL - mL;
        b[hh] = 0.01f * sL - mL;
    }

    f32x16 acc[2][4];
#pragma unroll
    for (int hh = 0; hh < 2; hh++)
#pragma unroll
        for (int nt = 0; nt < 4; nt++)
#pragma unroll
            for (int r = 0; r < 16; r++) acc[hh][nt][r] = 0.f;

    for (int jj0 = 0; jj0 < 64; jj0++) {
        int jbg = jh * 64 + jj0;
        unsigned int word = mrow[rowl * 131 + jbg];
#pragma unroll
        for (int s = 0; s < 2; s++) {
            int j16 = jbg * 2 + s;
            unsigned int mb = (word >> (s * 16 + jsub)) & 0xffu;
            bf16x8 P[2];
#pragma unroll
            for (int hh = 0; hh < 2; hh++) {
                const float* dp = &dstL[hh * 4096 + j16 * 16 + jsub];
                float4 d0 = *(const float4*)dp;
                float4 d1 = *(const float4*)(dp + 4);
                float dd[8] = {d0.x, d0.y, d0.z, d0.w, d1.x, d1.y, d1.z, d1.w};
                float pf[8];
#pragma unroll
                for (int jj = 0; jj < 8; jj++) {
                    float t1 = dd[jj] + a[hh];
                    float t2 = fmaf(0.01f, dd[jj], b[hh]);
                    float v = fmaxf(t1, t2);
                    float e = __builtin_amdgcn_exp2f(v);
                    pf[jj] = ((mb >> jj) & 1u) ? e : 0.f;
                    lacc[hh] += pf[jj];
                }
                // pack to bf16 by truncation: hi16(pf[2i]) | hi16(pf[2i+1])<<16
                union { unsigned int u[4]; bf16x8 v8; } pk;
#pragma unroll
                for (int i2 = 0; i2 < 4; i2++)
                    pk.u[i2] = __builtin_amdgcn_perm(__float_as_uint(pf[2 * i2 + 1]),
                                                     __float_as_uint(pf[2 * i2]),
                                                     0x07060302u);
                P[hh] = pk.v8;
            }
            const bf16x8* bp = &HB32[(size_t)j16 * 512 + (ch * 4) * 64 + lane];
#pragma unroll
            for (int nt = 0; nt < 4; nt++) {
                bf16x8 bv = bp[nt * 64];
                acc[0][nt] = __builtin_amdgcn_mfma_f32_32x32x16_bf16(P[0], bv, acc[0][nt], 0, 0, 0);
                acc[1][nt] = __builtin_amdgcn_mfma_f32_32x32x16_bf16(P[1], bv, acc[1][nt], 0, 0, 0);
            }
        }
    }

    // row sums: lanes r and r+32 cover disjoint j-subranges of the same row
    lacc[0] += __shfl_xor(lacc[0], 32);
    lacc[1] += __shfl_xor(lacc[1], 32);
    __syncthreads();  // loop phase done; smraw becomes accbuf

    if (ch == 0 && lane < 32) {
        l_all[jh][0][lane] = lacc[0];
        l_all[jh][1][lane] = lacc[1];
    }
    if (jh == 1) {
#pragma unroll
        for (int hh = 0; hh < 2; hh++)
#pragma unroll
            for (int nt = 0; nt < 4; nt++) {
                float* dp = accbuf + (size_t)(((ch * 2 + hh) * 4 + nt) * 16) * 64 + lane;
#pragma unroll
                for (int r = 0; r < 16; r++) dp[r * 64] = acc[hh][nt][r];
            }
    }
    __syncthreads();
    if (t < 32) {
#pragma unroll
        for (int hh = 0; hh < 2; hh++) {
            float lt = l_all[0][hh][t] + l_all[1][hh][t];
            linv_l[hh][t] = (lt > 0.f) ? 1.f / lt : 0.f;  // isolated row -> 0
        }
    }
    __syncthreads();

    if (jh == 0) {
#pragma unroll
        for (int hh = 0; hh < 2; hh++) {
            int khead = k0 + hh;
#pragma unroll
            for (int nt = 0; nt < 4; nt++) {
                const float* sp = accbuf + (size_t)(((ch * 2 + hh) * 4 + nt) * 16) * 64 + lane;
                int c = (ch * 4 + nt) * 32 + (lane & 31);
#pragma unroll
                for (int reg = 0; reg < 16; reg++) {
                    int rowloc = (reg & 3) + 8 * (reg >> 2) + 4 * (lane >> 5);
                    float v = (acc[hh][nt][reg] + sp[reg * 64]) * linv_l[hh][rowloc];
                    int i = i0 + rowloc;
                    if (MODE == 1) {
                        v += h[(size_t)i * HH + c];
                        v = (v > 0.f) ? v : (__expf(v) - 1.f);  // elu
                        ((short*)outp)[(size_t)i * KH + (size_t)khead * HH + c] = f2bf(v);
                    } else {
                        ((short*)outp)[(size_t)khead * NN * HH + (size_t)i * HH + c] = f2bf(v);
                    }
                }
            }
        }
    }
}

// ---------------- elu(avg of heads) column partial sums (bf16 planes) --------
__global__ void colsum_kernel(const float* __restrict__ h2,
                              const short* __restrict__ heads,
                              float* __restrict__ partial) {
    int c = threadIdx.x;
    int b = blockIdx.x;
    float s = 0.f;
    for (int il = 0; il < 64; il++) {
        int i = b * 64 + il;
        float v = h2[(size_t)i * HH + c];
#pragma unroll
        for (int k = 0; k < KK; k++) {
            unsigned int bits = (unsigned int)(unsigned short)heads[(size_t)k * NN * HH + (size_t)i * HH + c];
            v += 0.125f * __uint_as_float(bits << 16);
        }
        s += (v > 0.f) ? v : (__expf(v) - 1.f);
    }
    partial[b * HH + c] = s;
}

__global__ void final_kernel(const float* __restrict__ partial,
                             const float* __restrict__ out_w,
                             const float* __restrict__ out_b,
                             float* __restrict__ dout) {
    __shared__ float red[256];
    int c = threadIdx.x;
    float s = 0.f;
    for (int b = 0; b < 64; b++) s += partial[b * HH + c];
    red[c] = (s / 4096.f) * out_w[c];
    __syncthreads();
    for (int off = 128; off > 0; off >>= 1) {
        if (c < off) red[c] += red[c + off];
        __syncthreads();
    }
    if (c == 0) dout[0] = red[0] + out_b[0];
}

extern "C" void kernel_launch(void* const* d_in, const int* in_sizes, int n_in,
                              void* d_out, int out_size, void* d_ws, size_t ws_size,
                              hipStream_t stream) {
    (void)in_sizes; (void)n_in; (void)out_size; (void)ws_size;
    const float* adj   = (const float*)d_in[0];
    const float* feats = (const float*)d_in[1];
    const float* W1_w  = (const float*)d_in[2];
    const float* W1_b  = (const float*)d_in[3];
    const float* a1_w  = (const float*)d_in[4];
    const float* a1_b  = (const float*)d_in[5];
    const float* W2_w  = (const float*)d_in[6];
    const float* W2_b  = (const float*)d_in[7];
    const float* a2_w  = (const float*)d_in[8];
    const float* a2_b  = (const float*)d_in[9];
    const float* out_w = (const float*)d_in[10];
    const float* out_b = (const float*)d_in[11];

    char* w = (char*)d_ws;
    const size_t MB = 1ull << 20;
    unsigned int* mbits = (unsigned int*)(w);              // 0..2MB
    bf16x8* Aadj   = (bf16x8*)(w + 2 * MB);                // 2..34MB   (phase 1)
    short*  h1nb   = (short*)(w + 2 * MB);                 // 2..18MB   (phase 2: attn1 out bf16)
    bf16x8* h1na   = (bf16x8*)(w + 18 * MB);               // 18..34MB  (phase 2: A-frag)
    short*  planes = (short*)(w + 2 * MB);                 // 2..18MB   (phase 3: head planes bf16)
    bf16x8* Bfeats = (bf16x8*)(w + 34 * MB);               // 34..38MB  (phase 1)
    float*  h2     = (float*)(w + 34 * MB);                // 34..38MB  (phase 3)
    float*  tmp1   = (float*)(w + 38 * MB);                // 38..46MB  (phase 1)
    float*  h1     = (float*)(w + 38 * MB);                // 38..42MB  (phase 2; tmp1 dead)
    bf16x8* W1f    = (bf16x8*)(w + 42 * MB);               // 256 KB
    bf16x8* W2f    = (bf16x8*)(w + 42 * MB + 256 * 1024);  // 1 MB
    float*  srcT   = (float*)(w + 43 * MB + 256 * 1024);   // 128 KB
    float*  dstT   = (float*)(w + 43 * MB + 384 * 1024);   // 128 KB
    float*  maxd   = (float*)(w + 43 * MB + 512 * 1024);   // tiny
    bf16x8* HB32   = (bf16x8*)(w + 44 * MB);               // 44..46MB (2 MB)
    bf16x8* tmp1a  = (bf16x8*)(w + 46 * MB);               // 46..50MB
    float*  partial = (float*)(w + 50 * MB);               // 64 KB

    // --- phase 1: h1 = (A @ feats) @ W1^T + b1 ---
    cvt_adj_kernel<<<NN / 16, 256, 0, stream>>>(adj, Aadj, mbits);
    cvt_b_frag_kernel<FF><<<NN / 32, 256, 0, stream>>>(feats, Bfeats);
    gemm_frag_kernel<<<dim3(FF / 128, NN / 64), 256, 0, stream>>>(
        Aadj, Bfeats, nullptr, tmp1, NN / 32, FF / 16, FF);
    cvt_a_frag_kernel<float><<<NN / 16, 256, 0, stream>>>(tmp1, tmp1a, FF);
    cvt_bt_frag_kernel<<<HH / 16, 256, 0, stream>>>(W1_w, W1f, FF, HH / 16);
    gemm_frag_kernel<<<dim3(HH / 128, NN / 64), 256, 0, stream>>>(
        tmp1a, W1f, W1_b, h1, FF / 32, HH / 16, HH);

    // --- phase 2: layer-1 attention -> h1nb (bf16), then h2 ---
    prep_kernel<<<NN / 32, 256, 0, stream>>>(h1, a1_w, a1_b, HB32, srcT, dstT);
    maxdst_kernel<<<KK, 256, 0, stream>>>(dstT, maxd);
    attn32_kernel<1><<<dim3(NN / 32, KK / 2), 256, 0, stream>>>(
        h1, srcT, dstT, maxd, mbits, HB32, h1nb);
    cvt_a_frag_kernel<short><<<NN / 16, 256, 0, stream>>>(h1nb, h1na, KH);
    cvt_bt_frag_kernel<<<HH / 16, 256, 0, stream>>>(W2_w, W2f, KH, HH / 16);
    gemm_frag_kernel<<<dim3(HH / 128, NN / 64), 256, 0, stream>>>(
        h1na, W2f, W2_b, h2, KH / 32, HH / 16, HH);

    // --- phase 3: layer-2 attention -> bf16 head planes, reduce ---
    prep_kernel<<<NN / 32, 256, 0, stream>>>(h2, a2_w, a2_b, HB32, srcT, dstT);
    maxdst_kernel<<<KK, 256, 0, stream>>>(dstT, maxd);
    attn32_kernel<2><<<dim3(NN / 32, KK / 2), 256, 0, stream>>>(
        h2, srcT, dstT, maxd, mbits, HB32, planes);
    colsum_kernel<<<64, 256, 0, stream>>>(h2, planes, partial);
    final_kernel<<<1, 256, 0, stream>>>(partial, out_w, out_b, (float*)d_out);
}